// Round 13
// baseline (12349.885 us; speedup 1.0000x reference)
//
#include <hip/hip_runtime.h>
#include <math.h>

#define H   512
#define B   512
#define T   512
#define TGT 28

typedef __bf16 bf16x8 __attribute__((ext_vector_type(8)));
typedef float  f32x4  __attribute__((ext_vector_type(4)));
typedef unsigned short u16;

// ws byte offsets
#define OFF_WPH  0x000000u  // Wpack_hi 2MB (frag-linear bf16)
#define OFF_WPL  0x200000u  // Wpack_lo 2MB
#define OFF_HHI0 0x400000u  // 512KB h hi buf0   (zeroed)
#define OFF_HLO0 0x480000u  // 512KB h lo buf0   (zeroed)
#define OFF_SYNC 0x500000u  // 4KB   sync page   (zeroed)
#define OFF_HHI1 0x501000u  // 512KB h hi buf1
#define OFF_HLO1 0x581000u  // 512KB h lo buf1

// dynamic LDS: W hi 64KB + W lo 64KB = 131072B. Static: gatesT[4][64][20]
// (20480B) + flags -> ~149KB total -> exactly 1 WG/CU (proven launch shape).
#define SMEM_BYTES 131072

__device__ inline u16 f2bf(float x) {
    unsigned u = __builtin_bit_cast(unsigned, x);
    u += 0x7FFFu + ((u >> 16) & 1u);          // RNE
    return (u16)(u >> 16);
}
__device__ inline float bf2f(u16 h) {
    unsigned u = ((unsigned)h) << 16;
    return __builtin_bit_cast(float, u);
}
// fast activations (validated v5-v13: absmax 1.22e-4, = libm baseline)
__device__ inline float frcp(float x) {
    float r = __builtin_amdgcn_rcpf(x);
    return r * fmaf(-x, r, 2.0f);
}
__device__ inline float fsig(float x) {
    return frcp(1.0f + __expf(-x));
}
__device__ inline float ftanh(float x) {
    return fmaf(2.0f, fsig(2.0f * x), -1.0f);
}

// group barrier among 2 waves via LDS int flags (v13 mechanism, tripwired)
__device__ inline void group_barrier2(int* gb, int kk, int l, int seq) {
    if (l == 0)
        __hip_atomic_store(&gb[kk], seq, __ATOMIC_RELEASE,
                           __HIP_MEMORY_SCOPE_WORKGROUP);
    int guard = 0;
    for (;;) {
        int v = __hip_atomic_load(&gb[l & 1], __ATOMIC_ACQUIRE,
                                  __HIP_MEMORY_SCOPE_WORKGROUP);
        if (__all(v >= seq)) break;
        if (++guard > (1 << 17)) break;       // tripwire: clean fail, no hang
    }
}

// ---------------------------------------------------------------------------
// Pack W_hh frag-linear bf16 hi/lo.  idx: r(5)|q(2)|S(4)|l(6), 8 k each.
// g = q*512 + r*16 + (l&15) ; k = S*32 + (l>>4)*8
// ---------------------------------------------------------------------------
__global__ __launch_bounds__(256) void init_pack(const float* __restrict__ Whh,
                                                 u16* __restrict__ wph,
                                                 u16* __restrict__ wpl) {
    int idx = blockIdx.x * 256 + threadIdx.x;   // [0, 131072)
    int l  = idx & 63;
    int S  = (idx >> 6) & 15;
    int q  = (idx >> 10) & 3;
    int r  = idx >> 12;
    int g  = q * 512 + r * 16 + (l & 15);
    int k  = S * 32 + ((l >> 4) * 8);
    const float* src = Whh + (size_t)g * H + k;
    __align__(16) u16 hi8[8];
    __align__(16) u16 lo8[8];
#pragma unroll
    for (int j = 0; j < 8; ++j) {
        float w = src[j];
        u16 hb = f2bf(w);
        hi8[j] = hb;
        lo8[j] = f2bf(w - bf2f(hb));
    }
    *(uint4*)(wph + (size_t)idx * 8) = *(const uint4*)hi8;
    *(uint4*)(wpl + (size_t)idx * 8) = *(const uint4*)lo8;
}

// zero [OFF_HHI0, OFF_HHI1) = h buf0 hi/lo + sync page = 263168 dwords
__global__ __launch_bounds__(256) void init_state(unsigned* __restrict__ zbase) {
    int idx = blockIdx.x * 256 + threadIdx.x;
    if (idx < 263168) zbase[idx] = 0u;
}

// ---------------------------------------------------------------------------
// Persistent XCD-local LSTM, v14: 256 WGs x 512 thr (proven shape), each WG =
// FOUR independent 2-wave groups (g = wave>>1):
//   group g owns batch rows pb+g*16..+16 (disjoint), its own gates buffer,
//   its own 2-wave LDS flag barriers, its own XCD arrival counter.
//   Wave kk (= wave&1) computes a K-HALF (8 rolled s-iters, 96 MFMAs).
//   Reduce: kk0 writes, GB, kk1 adds, GB  (2 rounds, was 4).
// Extends v13's proven overlap (4180us, 2 groups): finer skew absorption,
// 2 fewer barriers/step, reduce-phase idleness 6/8 -> 1/2.
// NOTE numerics: cross-quarter K sums now accumulate in-register within the
// half -> not bit-identical to v13 (last-digit drift; threshold 4.26e-3).
// ---------------------------------------------------------------------------
__global__ __launch_bounds__(512, 1) void lstm_persistent(
    const u16* __restrict__ wph, const u16* __restrict__ wpl,
    u16* __restrict__ hhi0, u16* __restrict__ hlo0,
    u16* __restrict__ hhi1, u16* __restrict__ hlo1,
    int* __restrict__ sync, const float* __restrict__ seq,
    const float* __restrict__ Wih, const float* __restrict__ bih,
    const float* __restrict__ bhh)
{
    extern __shared__ char smem[];
    u16* wh = (u16*)smem;                          // 64KB
    u16* wl = wh + 32768;                          // 64KB
    __shared__ __align__(16) float gatesT[4][64][20];  // per-group [n2][m 0..15 +pad]
    __shared__ int gbar[4][2];                     // group barrier flags
    __shared__ int grel[4];                        // group release seq
    __shared__ int sh_pr[2];

    const int tid = threadIdx.x;
    const int l   = tid & 63;
    const int w   = tid >> 6;
    const int g   = w >> 1;                        // group 0..3 (16-row block)
    const int kk  = w & 1;                         // K-half 0/1

    // ---- partition assignment: physical XCD id + per-XCD slot ----
    if (tid == 0) {
        unsigned xcc;
        asm volatile("s_getreg_b32 %0, hwreg(HW_REG_XCC_ID)" : "=s"(xcc));
        int p = (int)(xcc & 7u);
        int r = __hip_atomic_fetch_add(&sync[p * 32], 1,
                                       __ATOMIC_RELAXED, __HIP_MEMORY_SCOPE_AGENT);
        sh_pr[0] = p;
        sh_pr[1] = r & 31;                         // 0..31 (pigeonhole: 1 WG/CU)
    }
    if (tid < 8) gbar[tid >> 1][tid & 1] = 0;
    if (tid < 4) grel[tid] = 0;
    __syncthreads();                               // prologue only
    const int p = sh_pr[0];
    const int r = sh_pr[1];
    int* arrp = &sync[256 + p * 64 + g * 16];      // per-GROUP arrival counter
    int* gb   = gbar[g];

    // ---- stage W slice (worker r) into LDS, once, all 512 threads ----
    {
        const uint4* gh = (const uint4*)(wph + (size_t)r * 32768);
        const uint4* gl = (const uint4*)(wpl + (size_t)r * 32768);
        uint4* sh = (uint4*)wh;
        uint4* sl = (uint4*)wl;
#pragma unroll
        for (int i = 0; i < 8; ++i) {
            int idx = tid + i * 512;               // 0..4095
            sh[idx] = gh[idx];
            sl[idx] = gl[idx];
        }
    }

    // ---- thread-resident cell constants (group-local thread index) ----
    const int lt   = tid & 127;                    // 0..127 within group
    const int cc   = lt & 15;
    const int m0   = lt >> 4;                      // 0..7
    const int kcol = r * 16 + cc;
    float wib[4], bb[4];
#pragma unroll
    for (int q = 0; q < 4; ++q) {
        int gg = q * 512 + kcol;
        wib[q] = Wih[gg];
        bb[q]  = bih[gg] + bhh[gg];
    }
    float cr0 = 0.0f, cr1 = 0.0f;
    const int pb = p * 64;
    const int b0 = pb + g * 16 + m0;               // group rows
    const int b1 = b0 + 8;

    const int arow0 = (pb + g * 16 + (l & 15)) * H;

    __syncthreads();                               // W staged (prologue only)

    for (int t = 0; t < T; ++t) {
        const u16* hih = (t & 1) ? hhi1 : hhi0;
        const u16* hil = (t & 1) ? hlo1 : hlo0;
        u16* hoh = (t & 1) ? hhi0 : hhi1;
        u16* hol = (t & 1) ? hlo0 : hlo1;

        float sv0 = seq[(size_t)b0 * T + t];
        float sv1 = seq[(size_t)b1 * T + t];

        f32x4 acc[4] = {};

        // ---- MFMA phase: rolled s-loop over the K-half (8 iters) ----
#pragma unroll 1
        for (int s = 0; s < 8; ++s) {
            const int S  = kk * 8 + s;
            const int ka = S * 32 + ((l >> 4) * 8);
            bf16x8 ah = *(const bf16x8*)(hih + arow0 + ka);
            bf16x8 al = *(const bf16x8*)(hil + arow0 + ka);
#pragma unroll
            for (int n = 0; n < 4; ++n) {
                const int fo = ((n * 16 + S) * 64 + l) * 8;
                bf16x8 bh = *(const bf16x8*)(wh + fo);
                bf16x8 bl = *(const bf16x8*)(wl + fo);
                acc[n] = __builtin_amdgcn_mfma_f32_16x16x32_bf16(ah, bh, acc[n], 0, 0, 0);
                acc[n] = __builtin_amdgcn_mfma_f32_16x16x32_bf16(ah, bl, acc[n], 0, 0, 0);
                acc[n] = __builtin_amdgcn_mfma_f32_16x16x32_bf16(al, bh, acc[n], 0, 0, 0);
            }
        }

        // ---- K reduction, 2 rounds, group-local barriers ----
        // D: col=lane&15 -> n2, row=(lane>>4)*4+reg -> m (4 consecutive, 0..15)
        const int base = t * 3;
        if (kk == 0) {
#pragma unroll
            for (int n = 0; n < 4; ++n) {
                const int n2 = n * 16 + (l & 15);
                const int mb = (l >> 4) << 2;
                *(f32x4*)&gatesT[g][n2][mb] = acc[n];
            }
        }
        group_barrier2(gb, kk, l, base + 1);
        if (kk == 1) {
#pragma unroll
            for (int n = 0; n < 4; ++n) {
                const int n2 = n * 16 + (l & 15);
                const int mb = (l >> 4) << 2;
                float* gp = &gatesT[g][n2][mb];
                f32x4 v = *(const f32x4*)gp;
                v += acc[n];
                *(f32x4*)gp = v;
            }
        }
        group_barrier2(gb, kk, l, base + 2);

        // ---- cell update: 2 cells/thread, c in registers, fast act ----
        {
            float pre[4];
#pragma unroll
            for (int q = 0; q < 4; ++q) pre[q] = gatesT[g][q * 16 + cc][m0] + fmaf(sv0, wib[q], bb[q]);
            float ig = fsig(pre[0]);
            float fg = fsig(pre[1]);
            float gg2 = ftanh(pre[2]);
            float og = fsig(pre[3]);
            cr0 = fg * cr0 + ig * gg2;
            float hv = og * ftanh(cr0);
            u16 hb = f2bf(hv);
            size_t ci = (size_t)b0 * H + kcol;
            hoh[ci] = hb;
            hol[ci] = f2bf(hv - bf2f(hb));
        }
        {
            float pre[4];
#pragma unroll
            for (int q = 0; q < 4; ++q) pre[q] = gatesT[g][q * 16 + cc][m0 + 8] + fmaf(sv1, wib[q], bb[q]);
            float ig = fsig(pre[0]);
            float fg = fsig(pre[1]);
            float gg2 = ftanh(pre[2]);
            float og = fsig(pre[3]);
            cr1 = fg * cr1 + ig * gg2;
            float hv = og * ftanh(cr1);
            u16 hb = f2bf(hv);
            size_t ci = (size_t)b1 * H + kcol;
            hoh[ci] = hb;
            hol[ci] = f2bf(hv - bf2f(hb));
        }

        // ---- per-GROUP XCD barrier (v13 protocol; skip after last step) ----
        if (t < T - 1) {
            asm volatile("s_waitcnt vmcnt(0)" ::: "memory");  // own h stores in L2
            group_barrier2(gb, kk, l, base + 3);              // group stores drained
            if (kk == 0 && l == 0) {
                __hip_atomic_fetch_add(arrp, 1, __ATOMIC_RELAXED,
                                       __HIP_MEMORY_SCOPE_AGENT);
                const int target = 32 * (t + 1);
                int guard = 0;
                while (__hip_atomic_load(arrp, __ATOMIC_RELAXED,
                                         __HIP_MEMORY_SCOPE_AGENT) < target) {
                    __builtin_amdgcn_s_sleep(1);
                    if (++guard > (1 << 18)) break;           // tripwire
                }
                __hip_atomic_store(&grel[g], t + 1, __ATOMIC_RELEASE,
                                   __HIP_MEMORY_SCOPE_WORKGROUP);
            }
            {
                int guard = 0;
                while (__hip_atomic_load(&grel[g], __ATOMIC_ACQUIRE,
                                         __HIP_MEMORY_SCOPE_WORKGROUP) < t + 1) {
                    if (++guard > (1 << 17)) break;           // tripwire
                }
            }
            asm volatile("buffer_inv sc0" ::: "memory");      // invalidate L1 only
        }
    }
}

// ---------------------------------------------------------------------------
// MLP head
// ---------------------------------------------------------------------------
__global__ __launch_bounds__(256) void head_kernel(const u16* __restrict__ hhi,
                                                   const u16* __restrict__ hlo,
                                                   const float* __restrict__ fc1w,
                                                   const float* __restrict__ fc1b,
                                                   const float* __restrict__ fc2w,
                                                   const float* __restrict__ fc2b,
                                                   float* __restrict__ out) {
    const int b = blockIdx.x;
    const int tid = threadIdx.x;
    __shared__ __align__(16) float hb[H];
    __shared__ float z[256];

    hb[tid]       = bf2f(hhi[(size_t)b * H + tid])       + bf2f(hlo[(size_t)b * H + tid]);
    hb[tid + 256] = bf2f(hhi[(size_t)b * H + tid + 256]) + bf2f(hlo[(size_t)b * H + tid + 256]);
    __syncthreads();

    float acc = fc1b[tid];
    const float4* wr = (const float4*)(fc1w + (size_t)tid * H);
    const float4* hr = (const float4*)hb;
#pragma unroll 4
    for (int kk = 0; kk < H / 4; ++kk) {
        float4 wv = wr[kk], hv = hr[kk];
        acc += wv.x * hv.x + wv.y * hv.y + wv.z * hv.z + wv.w * hv.w;
    }
    z[tid] = fmaxf(acc, 0.0f);
    __syncthreads();

    if (tid < TGT) {
        float a = fc2b[tid];
        const float* w2 = fc2w + (size_t)tid * 256;
#pragma unroll 8
        for (int j = 0; j < 256; ++j) a += z[j] * w2[j];
        out[(size_t)b * TGT + tid] = a;
    }
}

extern "C" void kernel_launch(void* const* d_in, const int* in_sizes, int n_in,
                              void* d_out, int out_size, void* d_ws, size_t ws_size,
                              hipStream_t stream) {
    const float* seq  = (const float*)d_in[0];
    const float* Wih  = (const float*)d_in[1];
    const float* Whh  = (const float*)d_in[2];
    const float* bih  = (const float*)d_in[3];
    const float* bhh  = (const float*)d_in[4];
    const float* fc1w = (const float*)d_in[5];
    const float* fc1b = (const float*)d_in[6];
    const float* fc2w = (const float*)d_in[7];
    const float* fc2b = (const float*)d_in[8];
    float* out = (float*)d_out;

    char* wsb = (char*)d_ws;
    u16* wph  = (u16*)(wsb + OFF_WPH);
    u16* wpl  = (u16*)(wsb + OFF_WPL);
    u16* hhi0 = (u16*)(wsb + OFF_HHI0);
    u16* hlo0 = (u16*)(wsb + OFF_HLO0);
    u16* hhi1 = (u16*)(wsb + OFF_HHI1);
    u16* hlo1 = (u16*)(wsb + OFF_HLO1);
    int* sync = (int*)(wsb + OFF_SYNC);

    init_pack<<<512, 256, 0, stream>>>(Whh, wph, wpl);
    init_state<<<1028, 256, 0, stream>>>((unsigned*)(wsb + OFF_HHI0));

    hipFuncSetAttribute((const void*)lstm_persistent,
                        hipFuncAttributeMaxDynamicSharedMemorySize, SMEM_BYTES);

    void* args[] = {(void*)&wph, (void*)&wpl, (void*)&hhi0, (void*)&hlo0,
                    (void*)&hhi1, (void*)&hlo1, (void*)&sync, (void*)&seq,
                    (void*)&Wih, (void*)&bih, (void*)&bhh};
    // proven launch shape: 256 WGs x 512 thr, 1 WG/CU
    hipLaunchCooperativeKernel((const void*)lstm_persistent, dim3(256), dim3(512),
                               args, SMEM_BYTES, stream);

    // T even -> final h in buffer 0
    head_kernel<<<B, 256, 0, stream>>>(hhi0, hlo0, fc1w, fc1b, fc2w, fc2b, out);
}

// Round 14
// 4175.479 us; speedup vs baseline: 2.9577x; 2.9577x over previous
//
#include <hip/hip_runtime.h>
#include <math.h>

#define H   512
#define B   512
#define T   512
#define TGT 28

typedef __bf16 bf16x8 __attribute__((ext_vector_type(8)));
typedef float  f32x4  __attribute__((ext_vector_type(4)));
typedef unsigned short u16;

// ws byte offsets
#define OFF_WPH  0x000000u  // Wpack_hi 2MB (frag-linear bf16)
#define OFF_WPL  0x200000u  // Wpack_lo 2MB
#define OFF_HHI0 0x400000u  // 512KB h hi buf0   (zeroed)
#define OFF_HLO0 0x480000u  // 512KB h lo buf0   (zeroed)
#define OFF_SYNC 0x500000u  // 4KB   sync page   (zeroed)
#define OFF_HHI1 0x501000u  // 512KB h hi buf1
#define OFF_HLO1 0x581000u  // 512KB h lo buf1

// dynamic LDS: W hi 64KB + W lo 64KB = 131072B. Static: gatesT[2][64][36]
// (18432B) + flags -> ~149.6KB total -> exactly 1 WG/CU (proven launch shape).
#define SMEM_BYTES 131072

__device__ inline u16 f2bf(float x) {
    unsigned u = __builtin_bit_cast(unsigned, x);
    u += 0x7FFFu + ((u >> 16) & 1u);          // RNE
    return (u16)(u >> 16);
}
__device__ inline float bf2f(u16 h) {
    unsigned u = ((unsigned)h) << 16;
    return __builtin_bit_cast(float, u);
}
// fast activations (validated v5-v13: absmax 1.22e-4, = libm baseline)
__device__ inline float frcp(float x) {
    float r = __builtin_amdgcn_rcpf(x);
    return r * fmaf(-x, r, 2.0f);
}
__device__ inline float fsig(float x) {
    return frcp(1.0f + __expf(-x));
}
__device__ inline float ftanh(float x) {
    return fmaf(2.0f, fsig(2.0f * x), -1.0f);
}

// group barrier among 4 waves via LDS int flags (v13 mechanism, tripwired)
__device__ inline void group_barrier(int* gb, int kh, int l, int seq) {
    if (l == 0)
        __hip_atomic_store(&gb[kh], seq, __ATOMIC_RELEASE,
                           __HIP_MEMORY_SCOPE_WORKGROUP);
    int guard = 0;
    for (;;) {
        int v = __hip_atomic_load(&gb[l & 3], __ATOMIC_ACQUIRE,
                                  __HIP_MEMORY_SCOPE_WORKGROUP);
        if (__all(v >= seq)) break;
        if (++guard > (1 << 17)) break;       // tripwire: clean fail, no hang
    }
}

// ---------------------------------------------------------------------------
// Pack W_hh frag-linear bf16 hi/lo.  idx: r(5)|q(2)|S(4)|l(6), 8 k each.
// g = q*512 + r*16 + (l&15) ; k = S*32 + (l>>4)*8
// ---------------------------------------------------------------------------
__global__ __launch_bounds__(256) void init_pack(const float* __restrict__ Whh,
                                                 u16* __restrict__ wph,
                                                 u16* __restrict__ wpl) {
    int idx = blockIdx.x * 256 + threadIdx.x;   // [0, 131072)
    int l  = idx & 63;
    int S  = (idx >> 6) & 15;
    int q  = (idx >> 10) & 3;
    int r  = idx >> 12;
    int g  = q * 512 + r * 16 + (l & 15);
    int k  = S * 32 + ((l >> 4) * 8);
    const float* src = Whh + (size_t)g * H + k;
    __align__(16) u16 hi8[8];
    __align__(16) u16 lo8[8];
#pragma unroll
    for (int j = 0; j < 8; ++j) {
        float w = src[j];
        u16 hb = f2bf(w);
        hi8[j] = hb;
        lo8[j] = f2bf(w - bf2f(hb));
    }
    *(uint4*)(wph + (size_t)idx * 8) = *(const uint4*)hi8;
    *(uint4*)(wpl + (size_t)idx * 8) = *(const uint4*)lo8;
}

// zero [OFF_HHI0, OFF_HHI1) = h buf0 hi/lo + sync page = 263168 dwords
__global__ __launch_bounds__(256) void init_state(unsigned* __restrict__ zbase) {
    int idx = blockIdx.x * 256 + threadIdx.x;
    if (idx < 263168) zbase[idx] = 0u;
}

// ---------------------------------------------------------------------------
// Persistent XCD-local LSTM, v15 = v13 (best passing, 4180us) + ANTI-PHASE
// STAGGER: group 1 delays ~half a step once before the t-loop. The two
// independent groups otherwise run phase-locked (identical periods, same
// start) and contend for the same pipes simultaneously; the offset is
// self-sustaining (groups are decoupled domains) and interleaves their
// phases. Arithmetic untouched -> absmax must be exactly 1.2207e-4.
// v14 post-mortem: 4-group variant regressed 3x; its per-group XCD counters
// were 64B apart (two groups per cache line -> atomic line ping-pong storm).
// v13's counters are 128B apart. Spin counters get one line each, verified.
// ---------------------------------------------------------------------------
__global__ __launch_bounds__(512, 1) void lstm_persistent(
    const u16* __restrict__ wph, const u16* __restrict__ wpl,
    u16* __restrict__ hhi0, u16* __restrict__ hlo0,
    u16* __restrict__ hhi1, u16* __restrict__ hlo1,
    int* __restrict__ sync, const float* __restrict__ seq,
    const float* __restrict__ Wih, const float* __restrict__ bih,
    const float* __restrict__ bhh)
{
    extern __shared__ char smem[];
    u16* wh = (u16*)smem;                          // 64KB
    u16* wl = wh + 32768;                          // 64KB
    __shared__ __align__(16) float gatesT[2][64][36];  // per-group [n2][m]
    __shared__ int gbar[2][4];                     // group barrier flags
    __shared__ int grel[2];                        // group release seq
    __shared__ int sh_pr[2];

    const int tid = threadIdx.x;
    const int l   = tid & 63;
    const int w   = tid >> 6;
    const int g   = w >> 2;                        // group 0/1 (row half)
    const int kh  = w & 3;                         // K-quarter 0..3

    // ---- partition assignment: physical XCD id + per-XCD slot ----
    if (tid == 0) {
        unsigned xcc;
        asm volatile("s_getreg_b32 %0, hwreg(HW_REG_XCC_ID)" : "=s"(xcc));
        int p = (int)(xcc & 7u);
        int r = __hip_atomic_fetch_add(&sync[p * 32], 1,
                                       __ATOMIC_RELAXED, __HIP_MEMORY_SCOPE_AGENT);
        sh_pr[0] = p;
        sh_pr[1] = r & 31;                         // 0..31 (pigeonhole: 1 WG/CU)
    }
    if (tid < 8) gbar[tid >> 2][tid & 3] = 0;
    if (tid < 2) grel[tid] = 0;
    __syncthreads();                               // prologue only
    const int p = sh_pr[0];
    const int r = sh_pr[1];
    int* arrp = &sync[256 + p * 64 + g * 32];      // per-GROUP counter, own line
    int* gb   = gbar[g];

    // ---- stage W slice (worker r) into LDS, once, all 512 threads ----
    {
        const uint4* gh = (const uint4*)(wph + (size_t)r * 32768);
        const uint4* gl = (const uint4*)(wpl + (size_t)r * 32768);
        uint4* sh = (uint4*)wh;
        uint4* sl = (uint4*)wl;
#pragma unroll
        for (int i = 0; i < 8; ++i) {
            int idx = tid + i * 512;               // 0..4095
            sh[idx] = gh[idx];
            sl[idx] = gl[idx];
        }
    }

    // ---- thread-resident cell constants (group-local thread index) ----
    const int lt   = tid & 255;                    // 0..255 within group
    const int cc   = lt & 15;
    const int m0   = lt >> 4;                      // 0..15
    const int kcol = r * 16 + cc;
    float wib[4], bb[4];
#pragma unroll
    for (int q = 0; q < 4; ++q) {
        int gg = q * 512 + kcol;
        wib[q] = Wih[gg];
        bb[q]  = bih[gg] + bhh[gg];
    }
    float cr0 = 0.0f, cr1 = 0.0f;
    const int pb = p * 64;
    const int b0 = pb + g * 32 + m0;               // group rows
    const int b1 = b0 + 16;

    const int arow0 = (pb + g * 32 + (l & 15)) * H;
    const int arow1 = arow0 + 16 * H;

    __syncthreads();                               // W staged (prologue only)

    // ---- one-time anti-phase stagger: group 1 starts ~half a step late ----
    if (g == 1) {
#pragma unroll 1
        for (int i = 0; i < 4; ++i) __builtin_amdgcn_s_sleep(32);  // ~8k clocks
    }

    for (int t = 0; t < T; ++t) {
        const u16* hih = (t & 1) ? hhi1 : hhi0;
        const u16* hil = (t & 1) ? hlo1 : hlo0;
        u16* hoh = (t & 1) ? hhi0 : hhi1;
        u16* hol = (t & 1) ? hlo0 : hlo1;

        float sv0 = seq[(size_t)b0 * T + t];
        float sv1 = seq[(size_t)b1 * T + t];

        f32x4 acc[2][4] = {};

        // ---- MFMA phase: rolled s-loop (v10 form) ----
#pragma unroll 1
        for (int s = 0; s < 4; ++s) {
            const int S  = kh * 4 + s;
            const int ka = S * 32 + ((l >> 4) * 8);
            bf16x8 a0h = *(const bf16x8*)(hih + arow0 + ka);
            bf16x8 a1h = *(const bf16x8*)(hih + arow1 + ka);
            bf16x8 a0l = *(const bf16x8*)(hil + arow0 + ka);
            bf16x8 a1l = *(const bf16x8*)(hil + arow1 + ka);
#pragma unroll
            for (int n = 0; n < 4; ++n) {
                const int fo = ((n * 16 + S) * 64 + l) * 8;
                bf16x8 bh = *(const bf16x8*)(wh + fo);
                bf16x8 bl = *(const bf16x8*)(wl + fo);
                acc[0][n] = __builtin_amdgcn_mfma_f32_16x16x32_bf16(a0h, bh, acc[0][n], 0, 0, 0);
                acc[1][n] = __builtin_amdgcn_mfma_f32_16x16x32_bf16(a1h, bh, acc[1][n], 0, 0, 0);
                acc[0][n] = __builtin_amdgcn_mfma_f32_16x16x32_bf16(a0h, bl, acc[0][n], 0, 0, 0);
                acc[1][n] = __builtin_amdgcn_mfma_f32_16x16x32_bf16(a1h, bl, acc[1][n], 0, 0, 0);
                acc[0][n] = __builtin_amdgcn_mfma_f32_16x16x32_bf16(a0l, bh, acc[0][n], 0, 0, 0);
                acc[1][n] = __builtin_amdgcn_mfma_f32_16x16x32_bf16(a1l, bh, acc[1][n], 0, 0, 0);
            }
        }

        // ---- K reduction, 4 rounds, GROUP-LOCAL barriers (order = v10) ----
        const int base = t * 5;
#pragma unroll
        for (int rr = 0; rr < 4; ++rr) {
            if (kh == rr) {
#pragma unroll
                for (int ms = 0; ms < 2; ++ms)
#pragma unroll
                    for (int n = 0; n < 4; ++n) {
                        const int n2 = n * 16 + (l & 15);
                        const int mb = ms * 16 + ((l >> 4) << 2);
                        float* gp = &gatesT[g][n2][mb];
                        if (rr == 0) {
                            *(f32x4*)gp = acc[ms][n];
                        } else {
                            f32x4 v = *(const f32x4*)gp;
                            v += acc[ms][n];
                            *(f32x4*)gp = v;
                        }
                    }
            }
            group_barrier(gb, kh, l, base + rr + 1);
        }

        // ---- cell update: 2 cells/thread, c in registers, fast act ----
        {
            float pre[4];
#pragma unroll
            for (int q = 0; q < 4; ++q) pre[q] = gatesT[g][q * 16 + cc][m0] + fmaf(sv0, wib[q], bb[q]);
            float ig = fsig(pre[0]);
            float fg = fsig(pre[1]);
            float gg2 = ftanh(pre[2]);
            float og = fsig(pre[3]);
            cr0 = fg * cr0 + ig * gg2;
            float hv = og * ftanh(cr0);
            u16 hb = f2bf(hv);
            size_t ci = (size_t)b0 * H + kcol;
            hoh[ci] = hb;
            hol[ci] = f2bf(hv - bf2f(hb));
        }
        {
            float pre[4];
#pragma unroll
            for (int q = 0; q < 4; ++q) pre[q] = gatesT[g][q * 16 + cc][m0 + 16] + fmaf(sv1, wib[q], bb[q]);
            float ig = fsig(pre[0]);
            float fg = fsig(pre[1]);
            float gg2 = ftanh(pre[2]);
            float og = fsig(pre[3]);
            cr1 = fg * cr1 + ig * gg2;
            float hv = og * ftanh(cr1);
            u16 hb = f2bf(hv);
            size_t ci = (size_t)b1 * H + kcol;
            hoh[ci] = hb;
            hol[ci] = f2bf(hv - bf2f(hb));
        }

        // ---- per-GROUP XCD barrier (skip after last step) ----
        if (t < T - 1) {
            asm volatile("s_waitcnt vmcnt(0)" ::: "memory");  // own h stores in L2
            group_barrier(gb, kh, l, base + 5);               // group stores drained
            if (kh == 0 && l == 0) {
                __hip_atomic_fetch_add(arrp, 1, __ATOMIC_RELAXED,
                                       __HIP_MEMORY_SCOPE_AGENT);
                const int target = 32 * (t + 1);
                int guard = 0;
                while (__hip_atomic_load(arrp, __ATOMIC_RELAXED,
                                         __HIP_MEMORY_SCOPE_AGENT) < target) {
                    __builtin_amdgcn_s_sleep(1);
                    if (++guard > (1 << 18)) break;           // tripwire
                }
                __hip_atomic_store(&grel[g], t + 1, __ATOMIC_RELEASE,
                                   __HIP_MEMORY_SCOPE_WORKGROUP);
            }
            {
                int guard = 0;
                while (__hip_atomic_load(&grel[g], __ATOMIC_ACQUIRE,
                                         __HIP_MEMORY_SCOPE_WORKGROUP) < t + 1) {
                    if (++guard > (1 << 17)) break;           // tripwire
                }
            }
            asm volatile("buffer_inv sc0" ::: "memory");      // invalidate L1 only
        }
    }
}

// ---------------------------------------------------------------------------
// MLP head
// ---------------------------------------------------------------------------
__global__ __launch_bounds__(256) void head_kernel(const u16* __restrict__ hhi,
                                                   const u16* __restrict__ hlo,
                                                   const float* __restrict__ fc1w,
                                                   const float* __restrict__ fc1b,
                                                   const float* __restrict__ fc2w,
                                                   const float* __restrict__ fc2b,
                                                   float* __restrict__ out) {
    const int b = blockIdx.x;
    const int tid = threadIdx.x;
    __shared__ __align__(16) float hb[H];
    __shared__ float z[256];

    hb[tid]       = bf2f(hhi[(size_t)b * H + tid])       + bf2f(hlo[(size_t)b * H + tid]);
    hb[tid + 256] = bf2f(hhi[(size_t)b * H + tid + 256]) + bf2f(hlo[(size_t)b * H + tid + 256]);
    __syncthreads();

    float acc = fc1b[tid];
    const float4* wr = (const float4*)(fc1w + (size_t)tid * H);
    const float4* hr = (const float4*)hb;
#pragma unroll 4
    for (int kk = 0; kk < H / 4; ++kk) {
        float4 wv = wr[kk], hv = hr[kk];
        acc += wv.x * hv.x + wv.y * hv.y + wv.z * hv.z + wv.w * hv.w;
    }
    z[tid] = fmaxf(acc, 0.0f);
    __syncthreads();

    if (tid < TGT) {
        float a = fc2b[tid];
        const float* w2 = fc2w + (size_t)tid * 256;
#pragma unroll 8
        for (int j = 0; j < 256; ++j) a += z[j] * w2[j];
        out[(size_t)b * TGT + tid] = a;
    }
}

extern "C" void kernel_launch(void* const* d_in, const int* in_sizes, int n_in,
                              void* d_out, int out_size, void* d_ws, size_t ws_size,
                              hipStream_t stream) {
    const float* seq  = (const float*)d_in[0];
    const float* Wih  = (const float*)d_in[1];
    const float* Whh  = (const float*)d_in[2];
    const float* bih  = (const float*)d_in[3];
    const float* bhh  = (const float*)d_in[4];
    const float* fc1w = (const float*)d_in[5];
    const float* fc1b = (const float*)d_in[6];
    const float* fc2w = (const float*)d_in[7];
    const float* fc2b = (const float*)d_in[8];
    float* out = (float*)d_out;

    char* wsb = (char*)d_ws;
    u16* wph  = (u16*)(wsb + OFF_WPH);
    u16* wpl  = (u16*)(wsb + OFF_WPL);
    u16* hhi0 = (u16*)(wsb + OFF_HHI0);
    u16* hlo0 = (u16*)(wsb + OFF_HLO0);
    u16* hhi1 = (u16*)(wsb + OFF_HHI1);
    u16* hlo1 = (u16*)(wsb + OFF_HLO1);
    int* sync = (int*)(wsb + OFF_SYNC);

    init_pack<<<512, 256, 0, stream>>>(Whh, wph, wpl);
    init_state<<<1028, 256, 0, stream>>>((unsigned*)(wsb + OFF_HHI0));

    hipFuncSetAttribute((const void*)lstm_persistent,
                        hipFuncAttributeMaxDynamicSharedMemorySize, SMEM_BYTES);

    void* args[] = {(void*)&wph, (void*)&wpl, (void*)&hhi0, (void*)&hlo0,
                    (void*)&hhi1, (void*)&hlo1, (void*)&sync, (void*)&seq,
                    (void*)&Wih, (void*)&bih, (void*)&bhh};
    // proven launch shape: 256 WGs x 512 thr, 1 WG/CU
    hipLaunchCooperativeKernel((const void*)lstm_persistent, dim3(256), dim3(512),
                               args, SMEM_BYTES, stream);

    // T even -> final h in buffer 0
    head_kernel<<<B, 256, 0, stream>>>(hhi0, hlo0, fc1w, fc1b, fc2w, fc2b, out);
}